// Round 9
// baseline (685.871 us; speedup 1.0000x reference)
//
#include <hip/hip_runtime.h>
#include <stdint.h>

#define BLOCK 256
#define CHPW  4                 // channels per wave (16 lanes each)
#define CHPB  16                // channels per block (4 waves)
#define SSTR  1032              // dwords per search channel in LDS (1024 + 8 pad)
#define KNCH  64                // dwords per kernel channel in LDS

__device__ __forceinline__ void gl_lds16(const float* g, float* l) {
    __builtin_amdgcn_global_load_lds(
        (__attribute__((address_space(1))) void*)(uintptr_t)g,
        (__attribute__((address_space(3))) void*)l, 16, 0, 0);
}
__device__ __forceinline__ void gl_lds4(const float* g, float* l) {
    __builtin_amdgcn_global_load_lds(
        (__attribute__((address_space(1))) void*)(uintptr_t)g,
        (__attribute__((address_space(3))) void*)l, 4, 0, 0);
}
#define WAITV(N) do { \
    asm volatile("s_waitcnt vmcnt(" #N ")" ::: "memory"); \
    __builtin_amdgcn_sched_barrier(0); \
} while (0)

__global__ __launch_bounds__(BLOCK, 2) void dwxcorr_kernel(
    const float* __restrict__ kern,
    const float* __restrict__ srch,
    float* __restrict__ out)
{
    __shared__ float s_s[CHPB * SSTR];   // 66,048 B
    __shared__ float s_k[CHPB * KNCH];   //  4,096 B   -> 2 blocks/CU

    const int tid  = threadIdx.x;
    const int w    = tid >> 6;
    const int lane = tid & 63;
    const int c0   = blockIdx.x * CHPB;
    const int lch0 = w * CHPW;

    // ---- stage (wave-private; no __syncthreads anywhere) ----
    // ops 1-8: search rows 0..15 of the wave's 4 channels
    #pragma unroll
    for (int c = 0; c < CHPW; ++c) {
        const float* gs = srch + (size_t)(c0 + lch0 + c) * 1024;
        float* ls = s_s + (lch0 + c) * SSTR;
        gl_lds16(gs + 0 * 256 + lane * 4, ls + 0 * 256);
        gl_lds16(gs + 1 * 256 + lane * 4, ls + 1 * 256);
    }
    // ops 9-12: kernel tiles
    #pragma unroll
    for (int c = 0; c < CHPW; ++c)
        gl_lds4(kern + (size_t)(c0 + lch0 + c) * 64 + lane,
                s_k + (lch0 + c) * KNCH);
    // ops 13-20: search rows 16..31
    #pragma unroll
    for (int c = 0; c < CHPW; ++c) {
        const float* gs = srch + (size_t)(c0 + lch0 + c) * 1024;
        float* ls = s_s + (lch0 + c) * SSTR;
        gl_lds16(gs + 2 * 256 + lane * 4, ls + 2 * 256);
        gl_lds16(gs + 3 * 256 + lane * 4, ls + 3 * 256);
    }

    const int traw = lane & 15;
    const int t    = (traw > 12) ? 12 : traw;   // clamp idle lanes (broadcast reads)
    const int lc   = lch0 + (lane >> 4);
    const int j0   = 2 * t;
    const float* sb = s_s + lc * SSTR + j0;
    const float* kb = s_k + lc * KNCH;

    WAITV(8);   // rows 0..15 + kernels resident; rows 16..31 still in flight

    float kk[64];
    #pragma unroll
    for (int q = 0; q < 16; ++q) {       // b128, 4-addr broadcast
        float4 kv = ((const float4*)kb)[q];
        kk[4*q+0] = kv.x; kk[4*q+1] = kv.y; kk[4*q+2] = kv.z; kk[4*q+3] = kv.w;
    }

    float a0[25], a1[25];
    #pragma unroll
    for (int i = 0; i < 25; ++i) { a0[i] = 0.0f; a1[i] = 0.0f; }

#define ROWBODY(r) do { \
        float wv[10]; \
        _Pragma("unroll") \
        for (int s = 0; s < 5; ++s) { \
            float2 v2 = *(const float2*)&sb[(r) * 32 + 2 * s]; \
            wv[2*s] = v2.x; wv[2*s+1] = v2.y; \
        } \
        const int lo = ((r) > 24) ? ((r) - 24) : 0; \
        const int hi = ((r) < 7) ? (r) : 7; \
        _Pragma("unroll") \
        for (int u = 0; u < 8; ++u) { \
            if (u >= lo && u <= hi) { \
                const int i = (r) - u; \
                _Pragma("unroll") \
                for (int v = 0; v < 8; ++v) { \
                    const float k = kk[u * 8 + v]; \
                    a0[i] = fmaf(k, wv[v],     a0[i]); \
                    a1[i] = fmaf(k, wv[v + 1], a1[i]); \
                } \
            } \
        } \
    } while (0)

    // phase 1: search rows 0..15 (hides the in-flight rows 16..31)
    #pragma unroll
    for (int r = 0; r < 16; ++r) ROWBODY(r);

    WAITV(0);   // rows 16..31 resident

    // phase 2: search rows 16..31
    #pragma unroll
    for (int r = 16; r < 32; ++r) ROWBODY(r);

    // ---- store: lane t owns cols 2t, 2t+1 (t<=12; col 25 invalid) ----
    float* ob = out + (size_t)(c0 + lc) * 625 + j0;
    if (traw < 12) {
        #pragma unroll
        for (int i = 0; i < 25; ++i) { ob[i * 25] = a0[i]; ob[i * 25 + 1] = a1[i]; }
    } else if (traw == 12) {
        #pragma unroll
        for (int i = 0; i < 25; ++i) ob[i * 25] = a0[i];
    }
}

extern "C" void kernel_launch(void* const* d_in, const int* in_sizes, int n_in,
                              void* d_out, int out_size, void* d_ws, size_t ws_size,
                              hipStream_t stream) {
    const float* kern = (const float*)d_in[0];   // (128,256,8,8)
    const float* srch = (const float*)d_in[1];   // (128,256,32,32)
    float* out = (float*)d_out;                  // (128,256,25,25)

    const int nch  = in_sizes[0] / 64;           // 32768
    const int grid = nch / CHPB;                 // 2048
    dwxcorr_kernel<<<grid, BLOCK, 0, stream>>>(kern, srch, out);
}

// Round 11
// 281.900 us; speedup vs baseline: 2.4330x; 2.4330x over previous
//
#include <hip/hip_runtime.h>
#include <stdint.h>

#define BLOCK 256
#define CHPW  4                 // channels per wave (16 lanes each)
#define CHPB  16                // channels per block (4 waves)
#define SSTR  1032              // dwords per search channel in LDS (1024 + 8 pad)
#define KSTR  72                // dwords per kernel channel in LDS (64 + 8 pad)

__device__ __forceinline__ void gl_lds16(const float* g, float* l) {
    __builtin_amdgcn_global_load_lds(
        (__attribute__((address_space(1))) void*)(uintptr_t)g,
        (__attribute__((address_space(3))) void*)l, 16, 0, 0);
}
__device__ __forceinline__ void gl_lds4(const float* g, float* l) {
    __builtin_amdgcn_global_load_lds(
        (__attribute__((address_space(1))) void*)(uintptr_t)g,
        (__attribute__((address_space(3))) void*)l, 4, 0, 0);
}
// Order-independent full drain: correctness must not depend on the scheduler's
// global_load_lds issue order (round 10 lesson: counted vmcnt(8) broke when
// the register allocator changed and staging ops got reordered).
#define WAITV0() do { \
    asm volatile("s_waitcnt vmcnt(0)" ::: "memory"); \
    __builtin_amdgcn_sched_barrier(0); \
} while (0)

// No min-waves bound: (256,2) caps VGPR at 128 -> spill catastrophe (round 9).
// ~150-190 VGPR still allows 2 waves/SIMD; LDS (69KB) pins 2 blocks/CU anyway.
__global__ __launch_bounds__(BLOCK) void dwxcorr_kernel(
    const float* __restrict__ kern,
    const float* __restrict__ srch,
    float* __restrict__ out)
{
    __shared__ float s_s[CHPB * SSTR];   // 66,048 B
    __shared__ float s_k[CHPB * KSTR];   //  4,608 B   -> 2 blocks/CU

    const int tid  = threadIdx.x;
    const int w    = tid >> 6;
    const int lane = tid & 63;
    const int c0   = blockIdx.x * CHPB;
    const int lch0 = w * CHPW;

    // ---- stage (wave-private; no __syncthreads anywhere): 20 vmem-lds ops ----
    #pragma unroll
    for (int c = 0; c < CHPW; ++c) {
        const float* gs = srch + (size_t)(c0 + lch0 + c) * 1024;
        float* ls = s_s + (lch0 + c) * SSTR;
        gl_lds16(gs + 0 * 256 + lane * 4, ls + 0 * 256);
        gl_lds16(gs + 1 * 256 + lane * 4, ls + 1 * 256);
        gl_lds16(gs + 2 * 256 + lane * 4, ls + 2 * 256);
        gl_lds16(gs + 3 * 256 + lane * 4, ls + 3 * 256);
        gl_lds4(kern + (size_t)(c0 + lch0 + c) * 64 + lane,
                s_k + (lch0 + c) * KSTR);
    }

    const int traw = lane & 15;
    const int t    = (traw > 12) ? 12 : traw;   // clamp idle lanes (harmless reads)
    const int lc   = lch0 + (lane >> 4);
    const int j0   = 2 * t;
    const float* sb = s_s + lc * SSTR + j0;
    const float* kb = s_k + lc * KSTR;

    WAITV0();   // everything resident; no ordering assumption

    float kk[64];
    #pragma unroll
    for (int q = 0; q < 16; ++q) {       // b128 broadcast per 16-lane group
        float4 kv = ((const float4*)kb)[q];
        kk[4*q+0] = kv.x; kk[4*q+1] = kv.y; kk[4*q+2] = kv.z; kk[4*q+3] = kv.w;
    }

    float a0[25], a1[25];
    #pragma unroll
    for (int i = 0; i < 25; ++i) { a0[i] = 0.0f; a1[i] = 0.0f; }

    #pragma unroll
    for (int r = 0; r < 32; ++r) {
        float wv[10];
        #pragma unroll
        for (int s = 0; s < 5; ++s) {    // 5 aligned ds_read_b64
            float2 v2 = *(const float2*)&sb[r * 32 + 2 * s];
            wv[2*s] = v2.x; wv[2*s+1] = v2.y;
        }
        const int lo = (r > 24) ? (r - 24) : 0;
        const int hi = (r < 7) ? r : 7;
        #pragma unroll
        for (int u = 0; u < 8; ++u) {
            if (u >= lo && u <= hi) {
                const int i = r - u;
                #pragma unroll
                for (int v = 0; v < 8; ++v) {
                    const float k = kk[u * 8 + v];
                    a0[i] = fmaf(k, wv[v],     a0[i]);
                    a1[i] = fmaf(k, wv[v + 1], a1[i]);
                }
            }
        }
    }

    // ---- store: lane t owns cols 2t, 2t+1 (t<=12; col 25 invalid) ----
    float* ob = out + (size_t)(c0 + lc) * 625 + j0;
    if (traw < 12) {
        #pragma unroll
        for (int i = 0; i < 25; ++i) { ob[i * 25] = a0[i]; ob[i * 25 + 1] = a1[i]; }
    } else if (traw == 12) {
        #pragma unroll
        for (int i = 0; i < 25; ++i) ob[i * 25] = a0[i];
    }
}

extern "C" void kernel_launch(void* const* d_in, const int* in_sizes, int n_in,
                              void* d_out, int out_size, void* d_ws, size_t ws_size,
                              hipStream_t stream) {
    const float* kern = (const float*)d_in[0];   // (128,256,8,8)
    const float* srch = (const float*)d_in[1];   // (128,256,32,32)
    float* out = (float*)d_out;                  // (128,256,25,25)

    const int nch  = in_sizes[0] / 64;           // 32768
    const int grid = nch / CHPB;                 // 2048
    dwxcorr_kernel<<<grid, BLOCK, 0, stream>>>(kern, srch, out);
}

// Round 12
// 237.034 us; speedup vs baseline: 2.8936x; 1.1893x over previous
//
#include <hip/hip_runtime.h>
#include <stdint.h>

#define BLOCK 256
#define CHPW  4                 // channels per wave (16 lanes each)
#define CHPB  16                // channels per block (4 waves)
#define SSTR  1032              // dwords per search channel in LDS (1024 + 8 pad)
#define KSTR  72                // dwords per kernel channel in LDS (64 + 8 pad)

__device__ __forceinline__ void gl_lds16(const float* g, float* l) {
    __builtin_amdgcn_global_load_lds(
        (__attribute__((address_space(1))) void*)(uintptr_t)g,
        (__attribute__((address_space(3))) void*)l, 16, 0, 0);
}
__device__ __forceinline__ void gl_lds4(const float* g, float* l) {
    __builtin_amdgcn_global_load_lds(
        (__attribute__((address_space(1))) void*)(uintptr_t)g,
        (__attribute__((address_space(3))) void*)l, 4, 0, 0);
}
// Order-independent full drain (round 10 lesson: counted vmcnt broke when
// the scheduler reordered staging ops).
#define WAITV0() do { \
    asm volatile("s_waitcnt vmcnt(0)" ::: "memory"); \
    __builtin_amdgcn_sched_barrier(0); \
} while (0)

// No min-waves bound: (256,2) caps VGPR at 128 -> spill (round 9).
// Round 11 lesson: without in-loop scheduling fences the compiler hoists all
// 160 ds_reads -> ~300 live regs -> 256-cap spill (750MB scratch writes).
// Fix: sched_barrier(0) every 4 rows bounds live range to ~170 regs.
__global__ __launch_bounds__(BLOCK) void dwxcorr_kernel(
    const float* __restrict__ kern,
    const float* __restrict__ srch,
    float* __restrict__ out)
{
    __shared__ float s_s[CHPB * SSTR];   // 66,048 B
    __shared__ float s_k[CHPB * KSTR];   //  4,608 B   -> 2 blocks/CU

    const int tid  = threadIdx.x;
    const int w    = tid >> 6;
    const int lane = tid & 63;
    const int c0   = blockIdx.x * CHPB;
    const int lch0 = w * CHPW;

    // ---- stage (wave-private; no __syncthreads anywhere): 20 vmem-lds ops ----
    #pragma unroll
    for (int c = 0; c < CHPW; ++c) {
        const float* gs = srch + (size_t)(c0 + lch0 + c) * 1024;
        float* ls = s_s + (lch0 + c) * SSTR;
        gl_lds16(gs + 0 * 256 + lane * 4, ls + 0 * 256);
        gl_lds16(gs + 1 * 256 + lane * 4, ls + 1 * 256);
        gl_lds16(gs + 2 * 256 + lane * 4, ls + 2 * 256);
        gl_lds16(gs + 3 * 256 + lane * 4, ls + 3 * 256);
        gl_lds4(kern + (size_t)(c0 + lch0 + c) * 64 + lane,
                s_k + (lch0 + c) * KSTR);
    }

    const int traw = lane & 15;
    const int t    = (traw > 12) ? 12 : traw;   // clamp idle lanes (harmless reads)
    const int lc   = lch0 + (lane >> 4);
    const int j0   = 2 * t;
    const float* sb = s_s + lc * SSTR + j0;
    const float* kb = s_k + lc * KSTR;

    WAITV0();   // everything resident; no ordering assumption

    float kk[64];
    #pragma unroll
    for (int q = 0; q < 16; ++q) {       // b128 broadcast per 16-lane group
        float4 kv = ((const float4*)kb)[q];
        kk[4*q+0] = kv.x; kk[4*q+1] = kv.y; kk[4*q+2] = kv.z; kk[4*q+3] = kv.w;
    }

    float a0[25], a1[25];
    #pragma unroll
    for (int i = 0; i < 25; ++i) { a0[i] = 0.0f; a1[i] = 0.0f; }

    // 8 chunks of 4 rows; sched_barrier between chunks pins register pressure.
    #pragma unroll
    for (int rc = 0; rc < 8; ++rc) {
        #pragma unroll
        for (int rr = 0; rr < 4; ++rr) {
            const int r = rc * 4 + rr;
            float wv[10];
            #pragma unroll
            for (int s = 0; s < 5; ++s) {    // 5 aligned ds_read_b64
                float2 v2 = *(const float2*)&sb[r * 32 + 2 * s];
                wv[2*s] = v2.x; wv[2*s+1] = v2.y;
            }
            const int lo = (r > 24) ? (r - 24) : 0;
            const int hi = (r < 7) ? r : 7;
            #pragma unroll
            for (int u = 0; u < 8; ++u) {
                if (u >= lo && u <= hi) {
                    const int i = r - u;
                    #pragma unroll
                    for (int v = 0; v < 8; ++v) {
                        const float k = kk[u * 8 + v];
                        a0[i] = fmaf(k, wv[v],     a0[i]);
                        a1[i] = fmaf(k, wv[v + 1], a1[i]);
                    }
                }
            }
        }
        __builtin_amdgcn_sched_barrier(0);   // no load hoisting across chunks
    }

    // ---- store: lane t owns cols 2t, 2t+1 (t<=12; col 25 invalid) ----
    float* ob = out + (size_t)(c0 + lc) * 625 + j0;
    if (traw < 12) {
        #pragma unroll
        for (int i = 0; i < 25; ++i) { ob[i * 25] = a0[i]; ob[i * 25 + 1] = a1[i]; }
    } else if (traw == 12) {
        #pragma unroll
        for (int i = 0; i < 25; ++i) ob[i * 25] = a0[i];
    }
}

extern "C" void kernel_launch(void* const* d_in, const int* in_sizes, int n_in,
                              void* d_out, int out_size, void* d_ws, size_t ws_size,
                              hipStream_t stream) {
    const float* kern = (const float*)d_in[0];   // (128,256,8,8)
    const float* srch = (const float*)d_in[1];   // (128,256,32,32)
    float* out = (float*)d_out;                  // (128,256,25,25)

    const int nch  = in_sizes[0] / 64;           // 32768
    const int grid = nch / CHPB;                 // 2048
    dwxcorr_kernel<<<grid, BLOCK, 0, stream>>>(kern, srch, out);
}

// Round 13
// 106.506 us; speedup vs baseline: 6.4398x; 2.2256x over previous
//
#include <hip/hip_runtime.h>
#include <stdint.h>

#define BLOCK 256
#define CHPB  8                 // channels per block
#define SSTR  1032              // dwords per search channel in LDS (1024 + 8 pad)
#define KSTR  72                // dwords per kernel channel in LDS (64 + 8 pad)

__device__ __forceinline__ void gl_lds16(const float* g, float* l) {
    __builtin_amdgcn_global_load_lds(
        (__attribute__((address_space(1))) void*)(uintptr_t)g,
        (__attribute__((address_space(3))) void*)l, 16, 0, 0);
}
__device__ __forceinline__ void gl_lds4(const float* g, float* l) {
    __builtin_amdgcn_global_load_lds(
        (__attribute__((address_space(1))) void*)(uintptr_t)g,
        (__attribute__((address_space(3))) void*)l, 4, 0, 0);
}

// One half of a channel's output rows: i in [I0, I0+NI), search rows [RLO, RHI].
// Live state by construction: acc 2*NI + wv 40 + kr 8 + addr  (~90 regs).
template<int I0, int NI, int RLO, int RHI>
__device__ __forceinline__ void compute_store(const float* sb, const float* kb,
                                              float* ob, int traw)
{
    float a0[NI], a1[NI];
    #pragma unroll
    for (int i = 0; i < NI; ++i) { a0[i] = 0.0f; a1[i] = 0.0f; }

    #pragma unroll
    for (int r0 = RLO; r0 <= RHI; r0 += 4) {      // chunks of 4 search rows
        float wv[4][10];
        #pragma unroll
        for (int rr = 0; rr < 4; ++rr) {
            const int r = r0 + rr;
            if (r <= RHI) {
                #pragma unroll
                for (int s = 0; s < 5; ++s) {     // 5 aligned ds_read_b64
                    float2 v2 = *(const float2*)&sb[r * 32 + 2 * s];
                    wv[rr][2*s] = v2.x; wv[rr][2*s+1] = v2.y;
                }
            }
        }
        #pragma unroll
        for (int u = 0; u < 8; ++u) {
            // compile-time: does any row of this chunk feed output via tap u?
            bool any = false;
            #pragma unroll
            for (int rr = 0; rr < 4; ++rr) {
                const int r = r0 + rr;
                if (r <= RHI && r - u >= I0 && r - u < I0 + NI) any = true;
            }
            if (any) {
                // kernel row u: 2 broadcast float4 reads (not held across chunks)
                float4 k0 = *(const float4*)&kb[u * 8];
                float4 k1 = *(const float4*)&kb[u * 8 + 4];
                const float kr[8] = {k0.x,k0.y,k0.z,k0.w,k1.x,k1.y,k1.z,k1.w};
                #pragma unroll
                for (int rr = 0; rr < 4; ++rr) {
                    const int r = r0 + rr;
                    const int i = r - u;
                    if (r <= RHI && i >= I0 && i < I0 + NI) {
                        #pragma unroll
                        for (int v = 0; v < 8; ++v) {
                            a0[i-I0] = fmaf(kr[v], wv[rr][v],     a0[i-I0]);
                            a1[i-I0] = fmaf(kr[v], wv[rr][v + 1], a1[i-I0]);
                        }
                    }
                }
            }
        }
    }

    if (traw < 12) {
        #pragma unroll
        for (int i = 0; i < NI; ++i) {
            ob[(I0 + i) * 25]     = a0[i];
            ob[(I0 + i) * 25 + 1] = a1[i];
        }
    } else if (traw == 12) {
        #pragma unroll
        for (int i = 0; i < NI; ++i) ob[(I0 + i) * 25] = a0[i];
    }
}

// No min-waves bound (r9: cap->spill). Working set ~90 regs: compiler should
// land <=128 -> 4 blocks/CU (35.3KB LDS) = 16 waves/CU.
__global__ __launch_bounds__(BLOCK) void dwxcorr_kernel(
    const float* __restrict__ kern,
    const float* __restrict__ srch,
    float* __restrict__ out)
{
    __shared__ float s_s[CHPB * SSTR];   // 33,024 B
    __shared__ float s_k[CHPB * KSTR];   //  2,304 B

    const int tid  = threadIdx.x;
    const int w    = tid >> 6;
    const int lane = tid & 63;
    const int c0   = blockIdx.x * CHPB;

    // ---- stage: wave w stages channels 2w, 2w+1 (10 vmem-lds ops) ----
    #pragma unroll
    for (int cc = 0; cc < 2; ++cc) {
        const int c = 2 * w + cc;
        const float* gs = srch + (size_t)(c0 + c) * 1024;
        float* ls = s_s + c * SSTR;
        gl_lds16(gs + 0 * 256 + lane * 4, ls + 0 * 256);
        gl_lds16(gs + 1 * 256 + lane * 4, ls + 1 * 256);
        gl_lds16(gs + 2 * 256 + lane * 4, ls + 2 * 256);
        gl_lds16(gs + 3 * 256 + lane * 4, ls + 3 * 256);
        gl_lds4(kern + (size_t)(c0 + c) * 64 + lane, s_k + c * KSTR);
    }
    asm volatile("s_waitcnt vmcnt(0)" ::: "memory");
    __syncthreads();   // cross-wave LDS dependency (wave pair shares channels)

    const int traw = lane & 15;
    const int t    = (traw > 12) ? 12 : traw;     // clamp idle lanes
    const int lc   = 4 * (w >> 1) + (lane >> 4);  // local channel 0..7
    const int j0   = 2 * t;
    const float* sb = s_s + lc * SSTR + j0;
    const float* kb = s_k + lc * KSTR;
    float* ob = out + (size_t)(c0 + lc) * 625 + j0;

    if ((w & 1) == 0)
        compute_store<0, 13, 0, 19>(sb, kb, ob, traw);   // output rows 0..12
    else
        compute_store<13, 12, 13, 31>(sb, kb, ob, traw); // output rows 13..24
}

extern "C" void kernel_launch(void* const* d_in, const int* in_sizes, int n_in,
                              void* d_out, int out_size, void* d_ws, size_t ws_size,
                              hipStream_t stream) {
    const float* kern = (const float*)d_in[0];   // (128,256,8,8)
    const float* srch = (const float*)d_in[1];   // (128,256,32,32)
    float* out = (float*)d_out;                  // (128,256,25,25)

    const int nch  = in_sizes[0] / 64;           // 32768
    const int grid = nch / CHPB;                 // 4096
    dwxcorr_kernel<<<grid, BLOCK, 0, stream>>>(kern, srch, out);
}